// Round 1
// 114.491 us; speedup vs baseline: 1.0569x; 1.0569x over previous
//
#include <hip/hip_runtime.h>
#include <math.h>

#define Bp 256
#define Tp 128
#define SDp 8
#define ADp 2
#define Hp 3
#define Kp 4
#define HIDp 256
#define QDp (SDp + ADp)       // 10
#define X1Dp (Hp * Kp + QDp)  // 22
#define X1LD 40               // X1s LDS row stride (bf16) — padded: 2-way banks on MFMA A reads
#define W1LD 40               // W1s LDS row stride (bf16)
#define H1LD 264              // h1 / W2s row stride (bf16): 528 B = 132 dwords ≡ 4 mod 32 → 2-way
#define LOG2E 1.4426950408889634f

typedef short bf16x8 __attribute__((ext_vector_type(8)));
typedef float f32x4  __attribute__((ext_vector_type(4)));

__device__ __forceinline__ unsigned short f2bf(float f) {
    unsigned u = __float_as_uint(f);
    unsigned r = (u + 0x7FFFu + ((u >> 16) & 1u)) >> 16;
    return (unsigned short)r;
}

// ---------------------------------------------------------------------------
// Fully fused: 1 block = 1 batch (128 positions), 512 threads (8 waves).
// Phase A  attention, 4-way j-split (jh = tid>>7), partials combined in LDS;
//          X1 row (bf16, 22 padded to 32) written to LDS X1s.
// Phase B  MLP1 via MFMA 16x16x32: h1 = relu(X1 @ W1s^T + b1) -> LDS h1s.
// Phase C  MLP2 in two 128-col halves: W2 half staged f32->bf16 into LDS W2s
//          (region aliased over phase-A scratch), 8 MFMA/K per col-tile,
//          relu + Wout reduction in-register, shfl-xor across l16, store out.
// No workspace, no inter-kernel traffic, one launch.
//
// LDS map (132 KB):
//   region1 [0, 67584):      h1s [128][264] bf16            (live B -> C)
//   region2 [67584, 135168): aliased scratch:
//     +0      part [3][128][17] f32 (26112 B)               (phase A)
//     +26112  s4   [128] float4     (2048 B)                (phase A)
//     +28160  wq   [120] f32                                (phase A)
//     +28640  wk   [48]  f32                                (phase A)
//     +28832  wv   [48]  f32                                (phase A)
//     +29024  W1s  [256][40] bf16  (20480 B)                (A-stage -> B)
//     +49504  X1s  [128][40] bf16  (10240 B)                (A -> B)
//     +0      W2s  [128][264] bf16 (67568 B)                (phase C only)
// ---------------------------------------------------------------------------
__global__ __launch_bounds__(512, 2) void fused_kernel(
    const float* __restrict__ state, const float* __restrict__ action,
    const float* __restrict__ Wk, const float* __restrict__ Wq,
    const float* __restrict__ Wv, const float* __restrict__ W1,
    const float* __restrict__ b1, const float* __restrict__ W2,
    const float* __restrict__ b2, const float* __restrict__ Wout,
    const float* __restrict__ bout, float* __restrict__ out)
{
    __shared__ __align__(16) char lds[135168];
    unsigned short* h1s = (unsigned short*)lds;
    char* R2 = lds + 67584;
    float*  part = (float*)(R2);
    float4* s4   = (float4*)(R2 + 26112);
    float*  wq   = (float*)(R2 + 28160);
    float*  wk   = (float*)(R2 + 28640);
    float*  wv   = (float*)(R2 + 28832);
    unsigned short* W1s = (unsigned short*)(R2 + 29024);
    unsigned short* X1s = (unsigned short*)(R2 + 49504);
    unsigned short* W2s = (unsigned short*)(R2);

    const int b    = blockIdx.x;
    const int tid  = threadIdx.x;
    const int t    = tid & 127;
    const int jh   = tid >> 7;        // 0..3 — quarter of the j-range
    const int lane = tid & 63;
    const int wave = tid >> 6;        // 0..7
    const int quad = lane >> 4;
    const int l16  = lane & 15;

    // ---- initial staging (disjoint thread ranges + all-thread W1 convert) ----
    if (tid < Tp) {
        s4[tid] = ((const float4*)(state + (size_t)b * Tp * SDp))[tid * 2];
    } else if (tid < Tp + 120) {
        wq[tid - Tp] = Wq[tid - Tp];
    } else if (tid < Tp + 168) {
        wk[tid - Tp - 120] = Wk[tid - Tp - 120];
    } else if (tid < Tp + 216) {
        wv[tid - Tp - 168] = Wv[tid - Tp - 168];
    }
    {
        const int row = tid >> 1, c0 = (tid & 1) * 16;
        const float* wr = W1 + row * X1Dp;
        #pragma unroll
        for (int i = 0; i < 16; ++i) {
            const int c = c0 + i;
            W1s[row * W1LD + c] = (c < X1Dp) ? f2bf(wr[c]) : (unsigned short)0;
        }
    }
    __syncthreads();

    // ---- phase A: attention ----
    float qs[QDp];
    {
        const float* srow = state + ((size_t)b * Tp + t) * SDp;
        #pragma unroll
        for (int d = 0; d < SDp; ++d) qs[d] = srow[d];
        const float* arow = action + ((size_t)b * Tp + t) * ADp;
        qs[8] = arow[0]; qs[9] = arow[1];
    }

    float q[Hp * Kp];
    #pragma unroll
    for (int r = 0; r < Hp * Kp; ++r) {
        float a = 0.f;
        #pragma unroll
        for (int d = 0; d < QDp; ++d) a += qs[d] * wq[r * QDp + d];
        q[r] = a;
    }
    // qkp[h][c] = (0.5*log2e) * sum_k q[h,k]*Wk[h*4+k][c]  (exp -> exp2 fold)
    float qkp[Hp * Kp];
    #pragma unroll
    for (int h = 0; h < Hp; ++h)
        #pragma unroll
        for (int c = 0; c < Kp; ++c) {
            float a = 0.f;
            #pragma unroll
            for (int k = 0; k < Kp; ++k) a += q[h * Kp + k] * wk[(h * Kp + k) * Kp + c];
            qkp[h * Kp + c] = 0.5f * LOG2E * a;
        }

    const float4 st = s4[t];
    float ch0[Hp];
    #pragma unroll
    for (int h = 0; h < Hp; ++h)
        ch0[h] = st.x * qkp[h*4] + st.y * qkp[h*4+1] + st.z * qkp[h*4+2] + st.w * qkp[h*4+3];

    float l[Hp] = {0.f, 0.f, 0.f};
    float accs[Hp][4] = {};
    const int j0 = jh * 32;
    for (int j = j0; j < j0 + 32; ++j) {
        const float4 sj = s4[j];                 // j uniform per wave -> LDS broadcast
        #pragma unroll
        for (int h = 0; h < Hp; ++h) {
            const float d = sj.x * qkp[h*4] + sj.y * qkp[h*4+1]
                          + sj.z * qkp[h*4+2] + sj.w * qkp[h*4+3] - ch0[h];
            const float e = (j == t) ? 0.f : exp2f(d);
            l[h] += e;
            accs[h][0] += e * sj.x; accs[h][1] += e * sj.y;
            accs[h][2] += e * sj.z; accs[h][3] += e * sj.w;
        }
    }

    if (jh > 0) {
        float* pp = part + ((jh - 1) * 128 + t) * 17;   // stride 17 dwords: conflict-free
        #pragma unroll
        for (int h = 0; h < Hp; ++h) {
            pp[h] = l[h];
            #pragma unroll
            for (int c = 0; c < Kp; ++c) pp[3 + h * 4 + c] = accs[h][c];
        }
    }
    __syncthreads();

    if (jh == 0) {
        unsigned short rowb[32] __attribute__((aligned(16)));
        #pragma unroll
        for (int h = 0; h < Hp; ++h) {
            float lt = l[h];
            float a0 = accs[h][0], a1 = accs[h][1], a2 = accs[h][2], a3 = accs[h][3];
            #pragma unroll
            for (int p = 0; p < 3; ++p) {
                const float* pp = part + (p * 128 + t) * 17;
                lt += pp[h];
                a0 += pp[3 + h*4 + 0]; a1 += pp[3 + h*4 + 1];
                a2 += pp[3 + h*4 + 2]; a3 += pp[3 + h*4 + 3];
            }
            const float inv = 1.f / lt;
            const float rb0 = a0 * inv - st.x;
            const float rb1 = a1 * inv - st.y;
            const float rb2 = a2 * inv - st.z;
            const float rb3 = a3 * inv - st.w;
            #pragma unroll
            for (int k = 0; k < Kp; ++k) {
                const int r = h * Kp + k;
                rowb[r] = f2bf(rb0 * wv[r*4] + rb1 * wv[r*4+1] + rb2 * wv[r*4+2] + rb3 * wv[r*4+3]);
            }
        }
        #pragma unroll
        for (int i = 0; i < QDp; ++i) rowb[Hp * Kp + i] = f2bf(qs[i]);
        #pragma unroll
        for (int i = X1Dp; i < 32; ++i) rowb[i] = 0;

        uint4* dst = (uint4*)(X1s + t * X1LD);
        const uint4* srcv = (const uint4*)rowb;
        #pragma unroll
        for (int i = 0; i < 4; ++i) dst[i] = srcv[i];
    }
    __syncthreads();

    // ---- phase B: MLP1 (8 waves x 16 rows) ----
    {
        const bf16x8 afr = *(const bf16x8*)&X1s[(wave * 16 + l16) * X1LD + quad * 8];
        for (int nt = 0; nt < 16; ++nt) {
            const bf16x8 bfr = *(const bf16x8*)&W1s[(nt * 16 + l16) * W1LD + quad * 8];
            f32x4 acc = {0.f, 0.f, 0.f, 0.f};
            acc = __builtin_amdgcn_mfma_f32_16x16x32_bf16(afr, bfr, acc, 0, 0, 0);
            const int col = nt * 16 + l16;
            const float bb = b1[col];
            #pragma unroll
            for (int r = 0; r < 4; ++r)
                h1s[(wave * 16 + quad * 4 + r) * H1LD + col] = f2bf(fmaxf(acc[r] + bb, 0.f));
        }
    }
    __syncthreads();   // h1 ready; W1s/X1s dead (region about to be overwritten by W2s)

    // ---- phase C: MLP2 + out, two 128-col halves with W2 staged in LDS ----
    bf16x8 A[8];
    #pragma unroll
    for (int ks = 0; ks < 8; ++ks)
        A[ks] = *(const bf16x8*)&h1s[(wave * 16 + l16) * H1LD + ks * 32 + quad * 8];

    float rsum[4] = {0.f, 0.f, 0.f, 0.f};
    const int srow8 = tid >> 6;
    const int c4    = tid & 63;
    #pragma unroll
    for (int chh = 0; chh < 2; ++chh) {
        if (chh) __syncthreads();              // half-0 reads of W2s complete
        #pragma unroll
        for (int pass = 0; pass < 16; ++pass) {
            const int r_loc = pass * 8 + srow8;
            const float4 v = *(const float4*)(W2 + ((size_t)(chh * 128 + r_loc)) * HIDp + c4 * 4);
            ushort4 o;
            o.x = f2bf(v.x); o.y = f2bf(v.y); o.z = f2bf(v.z); o.w = f2bf(v.w);
            *(ushort4*)&W2s[r_loc * H1LD + c4 * 4] = o;
        }
        __syncthreads();
        for (int nt = 0; nt < 8; ++nt) {
            const int col = chh * 128 + nt * 16 + l16;
            bf16x8 Bf[8];
            #pragma unroll
            for (int ks = 0; ks < 8; ++ks)
                Bf[ks] = *(const bf16x8*)&W2s[(nt * 16 + l16) * H1LD + ks * 32 + quad * 8];
            f32x4 acc = {0.f, 0.f, 0.f, 0.f};
            #pragma unroll
            for (int ks = 0; ks < 8; ++ks)
                acc = __builtin_amdgcn_mfma_f32_16x16x32_bf16(A[ks], Bf[ks], acc, 0, 0, 0);
            const float bb = b2[col];
            const float wo = Wout[col];
            #pragma unroll
            for (int r = 0; r < 4; ++r)
                rsum[r] += fmaxf(acc[r] + bb, 0.f) * wo;
        }
    }

    #pragma unroll
    for (int off = 1; off < 16; off <<= 1)
        #pragma unroll
        for (int r = 0; r < 4; ++r)
            rsum[r] += __shfl_xor(rsum[r], off, 64);

    if (l16 == 0) {
        const float bo = bout[0];
        #pragma unroll
        for (int r = 0; r < 4; ++r)
            out[(size_t)b * Tp + wave * 16 + quad * 4 + r] = rsum[r] + bo;
    }
}

extern "C" void kernel_launch(void* const* d_in, const int* in_sizes, int n_in,
                              void* d_out, int out_size, void* d_ws, size_t ws_size,
                              hipStream_t stream) {
    const float* state  = (const float*)d_in[0];
    const float* action = (const float*)d_in[1];
    const float* Wk     = (const float*)d_in[2];
    const float* Wq     = (const float*)d_in[3];
    const float* Wv     = (const float*)d_in[4];
    const float* W1     = (const float*)d_in[5];
    const float* b1     = (const float*)d_in[6];
    const float* W2     = (const float*)d_in[7];
    const float* b2     = (const float*)d_in[8];
    const float* Wout   = (const float*)d_in[9];
    const float* bout   = (const float*)d_in[10];
    float* out = (float*)d_out;

    (void)d_ws; (void)ws_size;  // workspace no longer used — fully LDS-resident

    fused_kernel<<<Bp, 512, 0, stream>>>(state, action, Wk, Wq, Wv, W1, b1,
                                         W2, b2, Wout, bout, out);
}